// Round 4
// baseline (99.555 us; speedup 1.0000x reference)
//
#include <hip/hip_runtime.h>

// Problem constants (from reference)
#define SEQLEN  128
#define NKV     8
#define BATCH   8
#define HD      128
#define MAXSEQ  4096

typedef float f32x4 __attribute__((ext_vector_type(4)));

constexpr int       HD4     = HD / 4;                                   // 32 float4 per head row
constexpr long long HALF_F4 = (long long)BATCH * NKV * BATCH * 0 + (long long)BATCH * NKV * MAXSEQ * HD4; // 2^23
constexpr int       UNROLL  = 4;

// R3 (97.0 us) + exactly ONE change: 4-way ILP. Batch 4 loads then 4 nt
// stores per grid-stride step so each wave keeps 4 reads in flight instead
// of 1 (R3 compiled to VGPR_Count=8 => strictly serial load->store chain).
// Mapping, grid, nt stores identical to R3.

__global__ __launch_bounds__(256) void kv_update_kernel(
    const f32x4* __restrict__ xk,     // [SEQLEN][NKV][BATCH][HD]
    const f32x4* __restrict__ xv,
    const f32x4* __restrict__ kpast,  // [BATCH][NKV][MAXSEQ][HD]
    const f32x4* __restrict__ vpast,
    const int*   __restrict__ plen_ptr,
    f32x4*       __restrict__ out)    // new_k ++ new_v, flat
{
    const int plen = *plen_ptr;
    const long long total  = 2 * HALF_F4;                          // 2^24 f4
    const long long stride = (long long)gridDim.x * blockDim.x;    // 2^19
    const long long i0     = (long long)blockIdx.x * blockDim.x + threadIdx.x;

    // total / (UNROLL*stride) = 8 exact iterations; every element covered once.
    for (long long i = i0; i < total; i += UNROLL * stride) {
        f32x4 v[UNROLL];
        #pragma unroll
        for (int u = 0; u < UNROLL; ++u) {
            const long long e = i + (long long)u * stride;
            long long rem = e;
            const f32x4* past = kpast;
            const f32x4* xnew = xk;
            if (rem >= HALF_F4) { rem -= HALF_F4; past = vpast; xnew = xv; }

            // rem = ((b*NKV + h)*MAXSEQ + s)*HD4 + d4
            const int       d4  = (int)(rem & (HD4 - 1));      // % 32
            const long long row = rem >> 5;                    // / 32
            const int       s   = (int)(row & (MAXSEQ - 1));   // % 4096
            const int       bh  = (int)(row >> 12);            // / 4096
            const int       h   = bh & (NKV - 1);
            const int       b   = bh >> 3;
            const int       sl  = s - plen;

            // branch-free per-element source select (single load either way)
            const f32x4* src = ((unsigned)sl < (unsigned)SEQLEN)
                ? &xnew[(long long)((sl * NKV + h) * BATCH + b) * HD4 + d4]
                : &past[rem];
            v[u] = *src;
        }
        #pragma unroll
        for (int u = 0; u < UNROLL; ++u) {
            __builtin_nontemporal_store(v[u], &out[i + (long long)u * stride]);
        }
    }
}

extern "C" void kernel_launch(void* const* d_in, const int* in_sizes, int n_in,
                              void* d_out, int out_size, void* d_ws, size_t ws_size,
                              hipStream_t stream) {
    const f32x4* xk    = (const f32x4*)d_in[0];
    const f32x4* xv    = (const f32x4*)d_in[1];
    const f32x4* kpast = (const f32x4*)d_in[2];
    const f32x4* vpast = (const f32x4*)d_in[3];
    const int*   plen  = (const int*)d_in[4];
    f32x4*       out   = (f32x4*)d_out;

    dim3 grid(2048), block(256);   // same as R3: 2^19 threads, 32 f4/thread
    kv_update_kernel<<<grid, block, 0, stream>>>(xk, xv, kpast, vpast, plen, out);
}